// Round 15
// baseline (882.454 us; speedup 1.0000x reference)
//
#include <hip/hip_runtime.h>
#include <math.h>

typedef __bf16 bf16_t;
typedef __bf16 bf16x8 __attribute__((ext_vector_type(8)));
typedef __bf16 bf16x4 __attribute__((ext_vector_type(4)));
typedef float f32x4 __attribute__((ext_vector_type(4)));

#define D_MODEL 2048
#define N_HEADS 16
#define HEAD_D 128
#define SEQ 2048
#define NTOK 4096   // B*T
#define DFF 8192
#define UPN 16384
#define PSTRIDE ((size_t)NTOK * D_MODEL)   // partial-buffer stride (elements)

#define GLDS16(g, l) __builtin_amdgcn_global_load_lds( \
    (const __attribute__((address_space(1))) void*)(g), \
    (__attribute__((address_space(3))) void*)(l), 16, 0, 0)

#define MFMA16(a, b, c) __builtin_amdgcn_mfma_f32_16x16x32_bf16((a), (b), (c), 0, 0, 0)

// ---------------- fused f32 -> bf16 convert (all 6 weights, one launch) ----------------
__device__ __forceinline__ void cvt_seg(const float* __restrict__ in,
                                        bf16_t* __restrict__ out, long n4) {
    long i = (long)blockIdx.x * 256 + threadIdx.x;
    long stride = (long)gridDim.x * 256;
    for (; i < n4; i += stride) {
        float4 f = ((const float4*)in)[i];
        bf16x4 v;
        v[0] = (bf16_t)f.x; v[1] = (bf16_t)f.y; v[2] = (bf16_t)f.z; v[3] = (bf16_t)f.w;
        ((bf16x4*)out)[i] = v;
    }
}
__global__ __launch_bounds__(256) void cvt6_kernel(
        const float* s0, bf16_t* d0, const float* s1, bf16_t* d1,
        const float* s2, bf16_t* d2, const float* s3, bf16_t* d3,
        const float* s4, bf16_t* d4, const float* s5, bf16_t* d5) {
    cvt_seg(s0, d0, (long)D_MODEL * D_MODEL / 4);
    cvt_seg(s1, d1, (long)D_MODEL * D_MODEL / 4);
    cvt_seg(s2, d2, (long)D_MODEL * D_MODEL / 4);
    cvt_seg(s3, d3, (long)D_MODEL * D_MODEL / 4);
    cvt_seg(s4, d4, (long)UPN * D_MODEL / 4);
    cvt_seg(s5, d5, (long)D_MODEL * DFF / 4);
}

// ---------------- RMSNorm ----------------
__global__ __launch_bounds__(256) void rmsnorm_kernel(const float* __restrict__ x,
                                                      const float* __restrict__ g,
                                                      bf16_t* __restrict__ out) {
    int row = blockIdx.x;
    const float* xr = x + (size_t)row * D_MODEL;
    int c0 = threadIdx.x * 8;
    float4 a = *(const float4*)&xr[c0];
    float4 b = *(const float4*)&xr[c0 + 4];
    float ss = a.x*a.x + a.y*a.y + a.z*a.z + a.w*a.w
             + b.x*b.x + b.y*b.y + b.z*b.z + b.w*b.w;
    #pragma unroll
    for (int off = 1; off < 64; off <<= 1) ss += __shfl_xor(ss, off);
    __shared__ float red[4];
    if ((threadIdx.x & 63) == 0) red[threadIdx.x >> 6] = ss;
    __syncthreads();
    float norm = rsqrtf((red[0] + red[1] + red[2] + red[3]) * (1.f / D_MODEL) + 1e-6f);
    float4 ga = *(const float4*)&g[c0];
    float4 gb = *(const float4*)&g[c0 + 4];
    bf16x8 o;
    o[0] = (bf16_t)(a.x * ga.x * norm); o[1] = (bf16_t)(a.y * ga.y * norm);
    o[2] = (bf16_t)(a.z * ga.z * norm); o[3] = (bf16_t)(a.w * ga.w * norm);
    o[4] = (bf16_t)(b.x * gb.x * norm); o[5] = (bf16_t)(b.y * gb.y * norm);
    o[6] = (bf16_t)(b.z * gb.z * norm); o[7] = (bf16_t)(b.w * gb.w * norm);
    *(bf16x8*)&out[(size_t)row * D_MODEL + c0] = o;
}

// ---------------- combine: out = r + p0 + p1 (bf16 partials) ----------------
__global__ __launch_bounds__(256) void combine3_kernel(const float* __restrict__ r,
        const bf16_t* __restrict__ p0, const bf16_t* __restrict__ p1,
        float* __restrict__ out, long n8) {
    long i = (long)blockIdx.x * 256 + threadIdx.x;
    long stride = (long)gridDim.x * 256;
    for (; i < n8; i += stride) {
        size_t e = (size_t)i * 8;
        float4 a0 = *(const float4*)&r[e];
        float4 a1 = *(const float4*)&r[e + 4];
        bf16x8 b0 = *(const bf16x8*)&p0[e];
        bf16x8 b1 = *(const bf16x8*)&p1[e];
        float4 o0, o1;
        o0.x = a0.x + (float)b0[0] + (float)b1[0];
        o0.y = a0.y + (float)b0[1] + (float)b1[1];
        o0.z = a0.z + (float)b0[2] + (float)b1[2];
        o0.w = a0.w + (float)b0[3] + (float)b1[3];
        o1.x = a1.x + (float)b0[4] + (float)b1[4];
        o1.y = a1.y + (float)b0[5] + (float)b1[5];
        o1.z = a1.z + (float)b0[6] + (float)b1[6];
        o1.w = a1.w + (float)b0[7] + (float)b1[7];
        *(float4*)&out[e] = o0;
        *(float4*)&out[e + 4] = o1;
    }
}

// ---------------- fused combine(2 partials) + RMSNorm ----------------
__global__ __launch_bounds__(256) void combine_rms_kernel(const float* __restrict__ r,
        const bf16_t* __restrict__ p0, const bf16_t* __restrict__ p1,
        const float* __restrict__ g, float* __restrict__ x1, bf16_t* __restrict__ h2) {
    int row = blockIdx.x;
    size_t rb = (size_t)row * D_MODEL;
    int c0 = threadIdx.x * 8;
    float4 a0 = *(const float4*)&r[rb + c0];
    float4 a1 = *(const float4*)&r[rb + c0 + 4];
    bf16x8 b0 = *(const bf16x8*)&p0[rb + c0];
    bf16x8 b1 = *(const bf16x8*)&p1[rb + c0];
    float v0 = a0.x + (float)b0[0] + (float)b1[0];
    float v1 = a0.y + (float)b0[1] + (float)b1[1];
    float v2 = a0.z + (float)b0[2] + (float)b1[2];
    float v3 = a0.w + (float)b0[3] + (float)b1[3];
    float v4 = a1.x + (float)b0[4] + (float)b1[4];
    float v5 = a1.y + (float)b0[5] + (float)b1[5];
    float v6 = a1.z + (float)b0[6] + (float)b1[6];
    float v7 = a1.w + (float)b0[7] + (float)b1[7];
    float4 w0; w0.x = v0; w0.y = v1; w0.z = v2; w0.w = v3;
    float4 w1; w1.x = v4; w1.y = v5; w1.z = v6; w1.w = v7;
    *(float4*)&x1[rb + c0] = w0;
    *(float4*)&x1[rb + c0 + 4] = w1;
    float ss = v0*v0 + v1*v1 + v2*v2 + v3*v3 + v4*v4 + v5*v5 + v6*v6 + v7*v7;
    #pragma unroll
    for (int off = 1; off < 64; off <<= 1) ss += __shfl_xor(ss, off);
    __shared__ float red[4];
    if ((threadIdx.x & 63) == 0) red[threadIdx.x >> 6] = ss;
    __syncthreads();
    float norm = rsqrtf((red[0] + red[1] + red[2] + red[3]) * (1.f / D_MODEL) + 1e-6f);
    float4 ga = *(const float4*)&g[c0];
    float4 gb = *(const float4*)&g[c0 + 4];
    bf16x8 o;
    o[0] = (bf16_t)(v0 * ga.x * norm); o[1] = (bf16_t)(v1 * ga.y * norm);
    o[2] = (bf16_t)(v2 * ga.z * norm); o[3] = (bf16_t)(v3 * ga.w * norm);
    o[4] = (bf16_t)(v4 * gb.x * norm); o[5] = (bf16_t)(v5 * gb.y * norm);
    o[6] = (bf16_t)(v6 * gb.z * norm); o[7] = (bf16_t)(v7 * gb.w * norm);
    *(bf16x8*)&h2[rb + c0] = o;
}

// ---------------- 256x256 GEMM, deep-staged 4-phase pipeline (r7 structure, FROZEN) ----
// 512 thr = 8 waves (2M x 4N), wave owns 128x64. LDS 128 KB (1 block/CU): [buf][khalf][256][32].
// Stage slots: P1: A1(t+1)  P2: B1(t+1)  P3: A0(t+2)  P4: B0(t+2)
// Waits: end-P2 vmcnt(8); end-P4 vmcnt(8) — drain loads issued 5-6 phases back.
// Tail: t=NKT-2 W2=vmcnt(4); t=NKT-1 W1=W2=vmcnt(0). Two barriers per K-tile.
// (8-barrier variants regressed twice — r8/r12 338µs vs this 313µs. FROZEN.)
// MODE 1 KSPLIT=2: bf16 partial per z.   MODE 2: upgate gelu(u)*v.
template<int MODE, int KSPLIT>
__global__ __launch_bounds__(512, 2)
void gemm256(const bf16_t* __restrict__ A, const bf16_t* __restrict__ W,
             void* __restrict__ o0, const float* __restrict__ res, int nbx, int K)
{
    __shared__ __align__(16) bf16_t ldsA[2 * 2 * 8192];
    __shared__ __align__(16) bf16_t ldsB[2 * 2 * 8192];
    const int tid = threadIdx.x;
    const int wave = tid >> 6, lane = tid & 63;
    const int lr = lane & 15, lg = lane >> 4;
    const int wm = wave >> 2, wn = wave & 3;

    const int nwg = gridDim.x, bid = blockIdx.x;
    const int cpx = nwg >> 3;
    const int s = (bid & 7) * cpx + (bid >> 3);
    const int by = s & 15, bx = s >> 4;      // by fast: B panel stays L2-resident per XCD
    const int bm0 = by * 256;
    const int bn0 = (MODE == 2) ? bx * 128 : bx * 256;
    const int z = (KSPLIT > 1) ? blockIdx.z : 0;
    const int Keff = K / KSPLIT, koff = z * Keff;

    const int rl = wave * 16 + (lane >> 2);                  // staging row 0..127
    const int gsw = ((lane & 3) ^ ((rl >> 1) & 3)) * 8;      // inverse-swizzled src granule
    const bf16_t* asrc = A + (size_t)(bm0 + rl) * K + koff + gsw;
    const bf16_t* bsrc;
    size_t bstep2;
    if constexpr (MODE == 2) {
        int grp = rl >> 6, wi = rl & 63;
        int brow = (wi < 32) ? (bn0 + grp * 32 + wi) : (DFF + bn0 + grp * 32 + (wi - 32));
        bsrc = W + (size_t)brow * K + koff + gsw;
        bstep2 = (size_t)64 * K;
    } else {
        bsrc = W + (size_t)(bn0 + rl) * K + koff + gsw;
        bstep2 = (size_t)128 * K;
    }

    auto stA = [&](int t, int kh) {
        char* d = (char*)ldsA + (((t & 1) * 2 + kh) * 16384) + wave * 1024 + lane * 16;
        const bf16_t* sp = asrc + (size_t)t * 64 + kh * 32;
        GLDS16(sp, d);
        GLDS16(sp + (size_t)128 * K, d + 8192);
    };
    auto stB = [&](int t, int kh) {
        char* d = (char*)ldsB + (((t & 1) * 2 + kh) * 16384) + wave * 1024 + lane * 16;
        const bf16_t* sp = bsrc + (size_t)t * 64 + kh * 32;
        GLDS16(sp, d);
        GLDS16(sp + bstep2, d + 8192);
    };

    f32x4 acc[8][4] = {};
    const int xg = (lg ^ ((lr >> 1) & 3)) * 8;
    const int NKT = Keff >> 6;

    stA(0, 0); stB(0, 0); stA(0, 1); stB(0, 1); stA(1, 0); stB(1, 0);
    asm volatile("s_waitcnt vmcnt(8)" ::: "memory");
    __builtin_amdgcn_s_barrier();

#define TILE_BODY(T, S1, S2, W1, W2)                                                    \
    {                                                                                   \
        const int t_ = (T);                                                             \
        const bf16_t* Ab = ldsA + ((t_ & 1) * 2) * 8192;                                \
        const bf16_t* Bb = ldsB + ((t_ & 1) * 2) * 8192;                                \
        bf16x8 a0[4], a1[4], b0[4], b1[4];                                              \
        _Pragma("unroll")                                                               \
        for (int i = 0; i < 4; ++i)                                                     \
            a0[i] = *(const bf16x8*)&Ab[(wm * 128 + i * 16 + lr) * 32 + xg];            \
        _Pragma("unroll")                                                               \
        for (int n = 0; n < 4; ++n)                                                     \
            b0[n] = *(const bf16x8*)&Bb[(wn * 64 + n * 16 + lr) * 32 + xg];             \
        if (S1) stA(t_ + 1, 1);                                                         \
        __builtin_amdgcn_s_setprio(1);                                                  \
        _Pragma("unroll")                                                               \
        for (int i = 0; i < 4; ++i)                                                     \
            _Pragma("unroll")                                                           \
            for (int n = 0; n < 4; ++n)                                                 \
                acc[i][n] = MFMA16(a0[i], b0[n], acc[i][n]);                            \
        __builtin_amdgcn_s_setprio(0);                                                  \
        _Pragma("unroll")                                                               \
        for (int i = 0; i < 4; ++i)                                                     \
            a1[i] = *(const bf16x8*)&Ab[(wm * 128 + (i + 4) * 16 + lr) * 32 + xg];      \
        if (S1) stB(t_ + 1, 1);                                                         \
        __builtin_amdgcn_s_setprio(1);                                                  \
        _Pragma("unroll")                                                               \
        for (int i = 0; i < 4; ++i)                                                     \
            _Pragma("unroll")                                                           \
            for (int n = 0; n < 4; ++n)                                                 \
                acc[i + 4][n] = MFMA16(a1[i], b0[n], acc[i + 4][n]);                    \
        __builtin_amdgcn_s_setprio(0);                                                  \
        asm volatile("s_waitcnt vmcnt(" W1 ")" ::: "memory");                           \
        __builtin_amdgcn_s_barrier();                                                   \
        _Pragma("unroll")                                                               \
        for (int i = 0; i < 4; ++i)                                                     \
            a0[i] = *(const bf16x8*)&Ab[8192 + (wm * 128 + i * 16 + lr) * 32 + xg];     \
        _Pragma("unroll")                                                               \
        for (int n = 0; n < 4; ++n)                                                     \
            b1[n] = *(const bf16x8*)&Bb[8192 + (wn * 64 + n * 16 + lr) * 32 + xg];      \
        if (S2) stA(t_ + 2, 0);                                                         \
        __builtin_amdgcn_s_setprio(1);                                                  \
        _Pragma("unroll")                                                               \
        for (int i = 0; i < 4; ++i)                                                     \
            _Pragma("unroll")                                                           \
            for (int n = 0; n < 4; ++n)                                                 \
                acc[i][n] = MFMA16(a0[i], b1[n], acc[i][n]);                            \
        __builtin_amdgcn_s_setprio(0);                                                  \
        _Pragma("unroll")                                                               \
        for (int i = 0; i < 4; ++i)                                                     \
            a1[i] = *(const bf16x8*)&Ab[8192 + (wm * 128 + (i + 4) * 16 + lr) * 32 + xg]; \
        if (S2) stB(t_ + 2, 0);                                                         \
        __builtin_amdgcn_s_setprio(1);                                                  \
        _Pragma("unroll")                                                               \
        for (int i = 0; i < 4; ++i)                                                     \
            _Pragma("unroll")                                                           \
            for (int n = 0; n < 4; ++n)                                                 \
                acc[i + 4][n] = MFMA16(a1[i], b1[n], acc[i + 4][n]);                    \
        __builtin_amdgcn_s_setprio(0);                                                  \
        asm volatile("s_waitcnt vmcnt(" W2 ")" ::: "memory");                           \
        __builtin_amdgcn_s_barrier();                                                   \
    }

    for (int t = 0; t < NKT - 2; ++t) TILE_BODY(t, true, true, "8", "8");
    TILE_BODY(NKT - 2, true, false, "8", "4");
    TILE_BODY(NKT - 1, false, false, "0", "0");
#undef TILE_BODY

    // ---------------- epilogue ----------------
    if constexpr (MODE == 1) {
        bf16_t* po = (bf16_t*)o0 + (size_t)z * PSTRIDE;
        #pragma unroll
        for (int m = 0; m < 8; ++m) {
            int grow = bm0 + wm * 128 + m * 16 + lg * 4;
            #pragma unroll
            for (int n = 0; n < 4; ++n) {
                int gcol = bn0 + wn * 64 + n * 16 + lr;
                #pragma unroll
                for (int r = 0; r < 4; ++r) {
                    size_t idx = (size_t)(grow + r) * D_MODEL + gcol;
                    po[idx] = (bf16_t)acc[m][n][r];
                }
            }
        }
    } else {
        #pragma unroll
        for (int m = 0; m < 8; ++m) {
            int grow = bm0 + wm * 128 + m * 16 + lg * 4;
            #pragma unroll
            for (int n = 0; n < 2; ++n) {
                int gcol = bn0 + wn * 32 + n * 16 + lr;
                #pragma unroll
                for (int r = 0; r < 4; ++r) {
                    float u = acc[m][n][r], vg = acc[m][n + 2][r];
                    float ge = 0.5f * u * (1.f + erff(u * 0.70710678118654752f));
                    ((bf16_t*)o0)[(size_t)(grow + r) * DFF + gcol] = (bf16_t)(ge * vg);
                }
            }
        }
    }
}

// ---------------- QKV GEMM: BM=128 x BN=256, 2-phase pipeline, 768 blocks (3 rounds) ----
// 8 waves (2M x 4N), wave owns 64x64, acc[4][4]. LDS 96 KB: A[buf][kh][128][32] (32 KB),
// B[buf][kh][256][32] (64 KB).  Phase = one kh: 8 ds_reads + stage slot + 16 MFMA.
// Stage slots: P1: A1(t+1)+B1(t+1) (3 loads)  P2: A0(t+2)+B0(t+2) (3 loads).
// Waits (FIFO-derived): end-P1 vmcnt(6); end-P2 vmcnt(6); tails 6/3 then 0/0.
// Prologue 9 loads, vmcnt(6). q scaled by 1/sqrt(HD); v scattered to [b,h,d,s].
__global__ __launch_bounds__(512, 2)
void gemm_qkv(const bf16_t* __restrict__ A, const bf16_t* __restrict__ W,
              bf16_t* __restrict__ qo, bf16_t* __restrict__ ko, bf16_t* __restrict__ vo,
              int K)
{
    __shared__ __align__(16) bf16_t ldsA[2 * 2 * 4096];
    __shared__ __align__(16) bf16_t ldsB[2 * 2 * 8192];
    const int tid = threadIdx.x;
    const int wave = tid >> 6, lane = tid & 63;
    const int lr = lane & 15, lg = lane >> 4;
    const int wm = wave >> 2, wn = wave & 3;

    const int bid = blockIdx.x;                 // 768 blocks
    const int s = (bid & 7) * 96 + (bid >> 3);
    const int by = s & 31, bx = s >> 5;         // by fast (32), bx 0..23 disjoint per XCD
    const int bm0 = by * 128, bn0 = bx * 256;

    const int rl = wave * 16 + (lane >> 2);                  // 0..127
    const int gsw = ((lane & 3) ^ ((rl >> 1) & 3)) * 8;
    const bf16_t* asrc = A + (size_t)(bm0 + rl) * K + gsw;
    const bf16_t* bsrc = W + (size_t)(bn0 + rl) * K + gsw;

    auto stA = [&](int t, int kh) {
        char* d = (char*)ldsA + (((t & 1) * 2 + kh) * 8192) + wave * 1024 + lane * 16;
        GLDS16(asrc + (size_t)t * 64 + kh * 32, d);
    };
    auto stB = [&](int t, int kh) {
        char* d = (char*)ldsB + (((t & 1) * 2 + kh) * 16384) + wave * 1024 + lane * 16;
        const bf16_t* sp = bsrc + (size_t)t * 64 + kh * 32;
        GLDS16(sp, d);
        GLDS16(sp + (size_t)128 * K, d + 8192);
    };

    f32x4 acc[4][4] = {};
    const int xg = (lg ^ ((lr >> 1) & 3)) * 8;
    const int NKT = K >> 6;

    stA(0, 0); stB(0, 0); stA(0, 1); stB(0, 1); stA(1, 0); stB(1, 0);   // 9 loads
    asm volatile("s_waitcnt vmcnt(6)" ::: "memory");
    __builtin_amdgcn_s_barrier();

#define QKV_TILE(T, S1, S2, W1, W2)                                                     \
    {                                                                                   \
        const int t_ = (T);                                                             \
        const bf16_t* Ab = ldsA + ((t_ & 1) * 2) * 4096;                                \
        const bf16_t* Bb = ldsB + ((t_ & 1) * 2) * 8192;                                \
        bf16x8 af[4], bfr[4];                                                           \
        /* P1: kh0 */                                                                   \
        _Pragma("unroll")                                                               \
        for (int i = 0; i < 4; ++i)                                                     \
            af[i] = *(const bf16x8*)&Ab[(wm * 64 + i * 16 + lr) * 32 + xg];             \
        _Pragma("unroll")                                                               \
        for (int n = 0; n < 4; ++n)                                                     \
            bfr[n] = *(const bf16x8*)&Bb[(wn * 64 + n * 16 + lr) * 32 + xg];            \
        if (S1) { stA(t_ + 1, 1); stB(t_ + 1, 1); }                                     \
        __builtin_amdgcn_s_setprio(1);                                                  \
        _Pragma("unroll")                                                               \
        for (int i = 0; i < 4; ++i)                                                     \
            _Pragma("unroll")                                                           \
            for (int n = 0; n < 4; ++n)                                                 \
                acc[i][n] = MFMA16(af[i], bfr[n], acc[i][n]);                           \
        __builtin_amdgcn_s_setprio(0);                                                  \
        asm volatile("s_waitcnt vmcnt(" W1 ")" ::: "memory");                           \
        __builtin_amdgcn_s_barrier();                                                   \
        /* P2: kh1 */                                                                   \
        _Pragma("unroll")                                                               \
        for (int i = 0; i < 4; ++i)                                                     \
            af[i] = *(const bf16x8*)&Ab[4096 + (wm * 64 + i * 16 + lr) * 32 + xg];      \
        _Pragma("unroll")                                                               \
        for (int n = 0; n < 4; ++n)                                                     \
            bfr[n] = *(const bf16x8*)&Bb[8192 + (wn * 64 + n * 16 + lr) * 32 + xg];     \
        if (S2) { stA(t_ + 2, 0); stB(t_ + 2, 0); }                                     \
        __builtin_amdgcn_s_setprio(1);                                                  \
        _Pragma("unroll")                                                               \
        for (int i = 0; i < 4; ++i)                                                     \
            _Pragma("unroll")                                                           \
            for (int n = 0; n < 4; ++n)                                                 \
                acc[i][n] = MFMA16(af[i], bfr[n], acc[i][n]);                           \
        __builtin_amdgcn_s_setprio(0);                                                  \
        asm volatile("s_waitcnt vmcnt(" W2 ")" ::: "memory");                           \
        __builtin_amdgcn_s_barrier();                                                   \
    }

    for (int t = 0; t < NKT - 2; ++t) QKV_TILE(t, true, true, "6", "6");
    QKV_TILE(NKT - 2, true, false, "6", "3");
    QKV_TILE(NKT - 1, false, false, "0", "0");
#undef QKV_TILE

    // epilogue: th 0=q (scaled), 1=k, 2=v scattered to [b,h,d,s]
    const float qs = 0.08838834764831845f;
    const int th = bn0 >> 11;
    #pragma unroll
    for (int m = 0; m < 4; ++m) {
        int grow = bm0 + wm * 64 + m * 16 + lg * 4;
        #pragma unroll
        for (int n = 0; n < 4; ++n) {
            int gcol = bn0 + wn * 64 + n * 16 + lr;
            int c = gcol & 2047;
            if (th == 0) {
                #pragma unroll
                for (int r = 0; r < 4; ++r)
                    qo[(size_t)(grow + r) * D_MODEL + c] = (bf16_t)(acc[m][n][r] * qs);
            } else if (th == 1) {
                #pragma unroll
                for (int r = 0; r < 4; ++r)
                    ko[(size_t)(grow + r) * D_MODEL + c] = (bf16_t)acc[m][n][r];
            } else {
                int hh = c >> 7, d = c & 127;
                int bb = grow >> 11, t0 = grow & 2047;
                bf16x4 st;
                #pragma unroll
                for (int r = 0; r < 4; ++r) st[r] = (bf16_t)acc[m][n][r];
                *(bf16x4*)&vo[((size_t)(bb * N_HEADS + hh) * HEAD_D + d) * SEQ + t0] = st;
            }
        }
    }
}

// ---------------- Flash attention (causal), Q-block 128, KV-block 64 ----------------
// Balanced qb pairing; T14 named-register prefetch; T13 defer-max; T5 setprio on MFMA.
#define SM_PV(svv, mr, lrr, oo)                                                         \
    {                                                                                   \
        float resc_[4]; bool dall_ = true;                                              \
        _Pragma("unroll")                                                               \
        for (int r = 0; r < 4; ++r) {                                                   \
            float mx = fmaxf(fmaxf(svv[0][r], svv[1][r]), fmaxf(svv[2][r], svv[3][r]));  \
            _Pragma("unroll")                                                           \
            for (int off = 1; off < 16; off <<= 1) mx = fmaxf(mx, __shfl_xor(mx, off)); \
            bool defer = __all(mx - mr[r] <= 8.f);                                      \
            float mnew = defer ? mr[r] : fmaxf(mr[r], mx);                              \
            resc_[r] = defer ? 1.f : __expf(mr[r] - mnew);                              \
            dall_ &= defer;                                                             \
            float sum = 0.f;                                                            \
            _Pragma("unroll")                                                           \
            for (int nb = 0; nb < 4; ++nb) {                                            \
                float p = __expf(svv[nb][r] - mnew);                                    \
                svv[nb][r] = p; sum += p;                                               \
            }                                                                           \
            _Pragma("unroll")                                                           \
            for (int off = 1; off < 16; off <<= 1) sum += __shfl_xor(sum, off);         \
            lrr[r] = lrr[r] * resc_[r] + sum; mr[r] = mnew;                             \
        }                                                                               \
        if (!dall_) {                                                                   \
            _Pragma("unroll")                                                           \
            for (int ob = 0; ob < 8; ++ob)                                              \
                _Pragma("unroll")                                                       \
                for (int r = 0; r < 4; ++r) oo[ob][r] *= resc_[r];                      \
        }                                                                               \
        _Pragma("unroll")                                                               \
        for (int nb = 0; nb < 4; ++nb)                                                  \
            _Pragma("unroll")                                                           \
            for (int r = 0; r < 4; ++r)                                                 \
                Ps[wave][(lg * 4 + r) * 72 + nb * 16 + lr] = (bf16_t)svv[nb][r];        \
        __builtin_amdgcn_s_setprio(1);                                                  \
        _Pragma("unroll")                                                               \
        for (int kk = 0; kk < 2; ++kk) {                                                \
            bf16x8 ap = *(const bf16x8*)&Ps[wave][lr * 72 + kk * 32 + lg * 8];          \
            _Pragma("unroll")                                                           \
            for (int ob = 0; ob < 8; ++ob) {                                            \
                bf16x8 bv = *(const bf16x8*)&Vts[(ob * 16 + lr) * 68 + kk * 32 + lg * 8]; \
                oo[ob] = MFMA16(ap, bv, oo[ob]);                                        \
            }                                                                           \
        }                                                                               \
        __builtin_amdgcn_s_setprio(0);                                                  \
    }

__global__ __launch_bounds__(256)
void attn_kernel(const bf16_t* __restrict__ Q, const bf16_t* __restrict__ K,
                 const bf16_t* __restrict__ Vt, bf16_t* __restrict__ Z)
{
    const int qb = blockIdx.z ? blockIdx.x : (gridDim.x - 1 - blockIdx.x);
    const int h = blockIdx.y, b = blockIdx.z;
    const int q0 = qb * 128;
    const int ktmax = 2 * qb + 1;
    const int tid = threadIdx.x, wave = tid >> 6, lane = tid & 63;
    const int lr = lane & 15, lg = lane >> 4;

    __shared__ __align__(16) bf16_t Qs[128 * 136];
    __shared__ __align__(16) bf16_t Ks[64 * 136];
    __shared__ __align__(16) bf16_t Vts[128 * 68];
    __shared__ __align__(16) bf16_t Ps[4][16 * 72];

    const size_t base = ((size_t)b * SEQ) * D_MODEL + (size_t)h * HEAD_D;
    const size_t vbase = (size_t)(b * N_HEADS + h) * HEAD_D * SEQ;

    const int kr = tid >> 4, kc = (tid & 15) * 8;
    const int vdr = tid >> 3, vc = (tid & 7) * 8;

    #pragma unroll
    for (int i = 0; i < 8; ++i)
        *(uint4*)&Qs[(kr + i * 16) * 136 + kc] =
            *(const uint4*)&Q[base + (size_t)(q0 + kr + i * 16) * D_MODEL + kc];

    uint4 k0g, k1g, k2g, k3g, v0g, v1g, v2g, v3g;
    const bf16_t* Kb = K + base + (size_t)kr * D_MODEL + kc;
    const bf16_t* Vb = Vt + vbase + (size_t)vdr * SEQ + vc;
    auto loadKV = [&](int kt) {
        const bf16_t* kp = Kb + (size_t)kt * 64 * D_MODEL;
        k0g = *(const uint4*)kp;
        k1g = *(const uint4*)(kp + (size_t)16 * D_MODEL);
        k2g = *(const uint4*)(kp + (size_t)32 * D_MODEL);
        k3g = *(const uint4*)(kp + (size_t)48 * D_MODEL);
        const bf16_t* vp = Vb + kt * 64;
        v0g = *(const uint4*)vp;
        v1g = *(const uint4*)(vp + (size_t)32 * SEQ);
        v2g = *(const uint4*)(vp + (size_t)64 * SEQ);
        v3g = *(const uint4*)(vp + (size_t)96 * SEQ);
    };
    loadKV(0);

    f32x4 oL[8] = {}, oH[8] = {};
    float mL[4], lL[4], mH[4], lH[4];
    #pragma unroll
    for (int r = 0; r < 4; ++r) { mL[r] = -1e30f; lL[r] = 0.f; mH[r] = -1e30f; lH[r] = 0.f; }

    for (int kt = 0; kt <= ktmax; ++kt) {
        __syncthreads();
        *(uint4*)&Ks[kr * 136 + kc] = k0g;
        *(uint4*)&Ks[(kr + 16) * 136 + kc] = k1g;
        *(uint4*)&Ks[(kr + 32) * 136 + kc] = k2g;
        *(uint4*)&Ks[(kr + 48) * 136 + kc] = k3g;
        *(uint4*)&Vts[vdr * 68 + vc] = v0g;
        *(uint4*)&Vts[(vdr + 32) * 68 + vc] = v1g;
        *(uint4*)&Vts[(vdr + 64) * 68 + vc] = v2g;
        *(uint4*)&Vts[(vdr + 96) * 68 + vc] = v3g;
        __syncthreads();
        if (kt < ktmax) loadKV(kt + 1);

        if (kt < ktmax) {
            f32x4 sv[4] = {};
            __builtin_amdgcn_s_setprio(1);
            #pragma unroll
            for (int kk = 0; kk < 4; ++kk) {
                bf16x8 aq = *(const bf16x8*)&Qs[(wave * 16 + lr) * 136 + kk * 32 + lg * 8];
                #pragma unroll
                for (int nb = 0; nb < 4; ++nb) {
                    bf16x8 bk = *(const bf16x8*)&Ks[(nb * 16 + lr) * 136 + kk * 32 + lg * 8];
                    sv[nb] = MFMA16(aq, bk, sv[nb]);
                }
            }
            __builtin_amdgcn_s_setprio(0);
            if (kt == ktmax - 1) {
                #pragma unroll
                for (int nb = 0; nb < 4; ++nb)
                    #pragma unroll
                    for (int r = 0; r < 4; ++r) {
                        int qrel = 16 * wave + lg * 4 + r;
                        int krel = nb * 16 + lr;
                        if (krel > qrel) sv[nb][r] = -1e30f;
                    }
            }
            SM_PV(sv, mL, lL, oL)
        }
        {
            f32x4 sv[4] = {};
            __builtin_amdgcn_s_setprio(1);
            #pragma unroll
            for (int kk = 0; kk < 4; ++kk) {
                bf16x8 aq = *(const bf16x8*)&Qs[(64 + wave * 16 + lr) * 136 + kk * 32 + lg * 8];
                #pragma unroll
                for (int nb = 0; nb < 4; ++nb) {
                    bf16x8 bk = *(const bf16x8*)&Ks[(nb * 16 + lr) * 136 + kk * 32 + lg * 8];
                    sv[nb] = MFMA16(aq, bk, sv[nb]);
                }
            }
            __builtin_amdgcn_s_setprio(0);
            if (kt == ktmax) {
                #pragma unroll
                for (int nb = 0; nb < 4; ++nb)
                    #pragma unroll
                    for (int r = 0; r < 4; ++r) {
                        int qrel = 16 * wave + lg * 4 + r;
                        int krel = nb * 16 + lr;
                        if (krel > qrel) sv[nb][r] = -1e30f;
                    }
            }
            SM_PV(sv, mH, lH, oH)
        }
    }
    #pragma unroll
    for (int r = 0; r < 4; ++r) { lL[r] = 1.f / lL[r]; lH[r] = 1.f / lH[r]; }
    #pragma unroll
    for (int ob = 0; ob < 8; ++ob)
        #pragma unroll
        for (int r = 0; r < 4; ++r) {
            int t = q0 + 16 * wave + lg * 4 + r;
            Z[base + (size_t)t * D_MODEL + ob * 16 + lr] = (bf16_t)(oL[ob][r] * lL[r]);
            Z[base + (size_t)(t + 64) * D_MODEL + ob * 16 + lr] = (bf16_t)(oH[ob][r] * lH[r]);
        }
}
#undef SM_PV

// ---------------- host launch ----------------
extern "C" void kernel_launch(void* const* d_in, const int* in_sizes, int n_in,
                              void* d_out, int out_size, void* d_ws, size_t ws_size,
                              hipStream_t stream)
{
    const float* x   = (const float*)d_in[0];
    const float* g1  = (const float*)d_in[1];
    const float* wq  = (const float*)d_in[2];
    const float* wk  = (const float*)d_in[3];
    const float* wv  = (const float*)d_in[4];
    const float* wo  = (const float*)d_in[5];
    const float* g2  = (const float*)d_in[6];
    const float* wup = (const float*)d_in[7];
    const float* wdn = (const float*)d_in[8];
    float* out = (float*)d_out;

    char* wsp = (char*)d_ws;
    size_t off = 0;
    auto alloc = [&](size_t bytes) { void* p = wsp + off; off += (bytes + 255) & ~255ull; return p; };
    bf16_t* wq_b  = (bf16_t*)alloc((size_t)D_MODEL * D_MODEL * 2);
    bf16_t* wk_b  = (bf16_t*)alloc((size_t)D_MODEL * D_MODEL * 2);
    bf16_t* wv_b  = (bf16_t*)alloc((size_t)D_MODEL * D_MODEL * 2);
    bf16_t* wo_b  = (bf16_t*)alloc((size_t)D_MODEL * D_MODEL * 2);
    bf16_t* wup_b = (bf16_t*)alloc((size_t)UPN * D_MODEL * 2);
    bf16_t* wdn_b = (bf16_t*)alloc((size_t)D_MODEL * DFF * 2);
    bf16_t* h_b   = (bf16_t*)alloc((size_t)NTOK * D_MODEL * 2);
    bf16_t* q_b   = (bf16_t*)alloc((size_t)NTOK * D_MODEL * 2);
    bf16_t* k_b   = (bf16_t*)alloc((size_t)NTOK * D_MODEL * 2);
    bf16_t* vt_b  = (bf16_t*)alloc((size_t)NTOK * D_MODEL * 2);   // [b,h,d,s]
    bf16_t* z_b   = (bf16_t*)alloc((size_t)NTOK * D_MODEL * 2);
    float*  x1    = (float*) alloc((size_t)NTOK * D_MODEL * 4);
    bf16_t* h2_b  = (bf16_t*)alloc((size_t)NTOK * D_MODEL * 2);
    bf16_t* act_b = (bf16_t*)alloc((size_t)NTOK * DFF * 2);
    bf16_t* pbuf = h_b;   // split-K partials reuse h_b+q_b (dead then)

    cvt6_kernel<<<2048, 256, 0, stream>>>(wq, wq_b, wk, wk_b, wv, wv_b,
                                          wo, wo_b, wup, wup_b, wdn, wdn_b);

    rmsnorm_kernel<<<NTOK, 256, 0, stream>>>(x, g1, h_b);

    // fused QKV: BM=128, 768 blocks = 3 full rounds
    gemm_qkv<<<768, 512, 0, stream>>>(h_b, wq_b, q_b, k_b, vt_b, D_MODEL);

    attn_kernel<<<dim3(SEQ / 128, N_HEADS, 2), 256, 0, stream>>>(q_b, k_b, vt_b, z_b);

    gemm256<1, 2><<<dim3(8 * 16, 1, 2), 512, 0, stream>>>(z_b, wo_b, pbuf, nullptr, 8, D_MODEL);
    combine_rms_kernel<<<NTOK, 256, 0, stream>>>(x, pbuf, pbuf + PSTRIDE, g2, x1, h2_b);

    gemm256<2, 1><<<64 * 16, 512, 0, stream>>>(h2_b, wup_b, act_b, nullptr, 64, D_MODEL);

    gemm256<1, 2><<<dim3(8 * 16, 1, 2), 512, 0, stream>>>(act_b, wdn_b, pbuf, nullptr, 8, DFF);
    combine3_kernel<<<2048, 256, 0, stream>>>(x1, pbuf, pbuf + PSTRIDE, out,
                                              (long)NTOK * D_MODEL / 8);
}

// Round 16
// 877.799 us; speedup vs baseline: 1.0053x; 1.0053x over previous
//
#include <hip/hip_runtime.h>
#include <math.h>

typedef __bf16 bf16_t;
typedef __bf16 bf16x8 __attribute__((ext_vector_type(8)));
typedef __bf16 bf16x4 __attribute__((ext_vector_type(4)));
typedef float f32x4 __attribute__((ext_vector_type(4)));

#define D_MODEL 2048
#define N_HEADS 16
#define HEAD_D 128
#define SEQ 2048
#define NTOK 4096   // B*T
#define DFF 8192
#define UPN 16384
#define PSTRIDE ((size_t)NTOK * D_MODEL)   // partial-buffer stride (elements)

#define GLDS16(g, l) __builtin_amdgcn_global_load_lds( \
    (const __attribute__((address_space(1))) void*)(g), \
    (__attribute__((address_space(3))) void*)(l), 16, 0, 0)

#define MFMA16(a, b, c) __builtin_amdgcn_mfma_f32_16x16x32_bf16((a), (b), (c), 0, 0, 0)

// ---------------- fused f32 -> bf16 convert (all 6 weights, one launch) ----------------
__device__ __forceinline__ void cvt_seg(const float* __restrict__ in,
                                        bf16_t* __restrict__ out, long n4) {
    long i = (long)blockIdx.x * 256 + threadIdx.x;
    long stride = (long)gridDim.x * 256;
    for (; i < n4; i += stride) {
        float4 f = ((const float4*)in)[i];
        bf16x4 v;
        v[0] = (bf16_t)f.x; v[1] = (bf16_t)f.y; v[2] = (bf16_t)f.z; v[3] = (bf16_t)f.w;
        ((bf16x4*)out)[i] = v;
    }
}
__global__ __launch_bounds__(256) void cvt6_kernel(
        const float* s0, bf16_t* d0, const float* s1, bf16_t* d1,
        const float* s2, bf16_t* d2, const float* s3, bf16_t* d3,
        const float* s4, bf16_t* d4, const float* s5, bf16_t* d5) {
    cvt_seg(s0, d0, (long)D_MODEL * D_MODEL / 4);
    cvt_seg(s1, d1, (long)D_MODEL * D_MODEL / 4);
    cvt_seg(s2, d2, (long)D_MODEL * D_MODEL / 4);
    cvt_seg(s3, d3, (long)D_MODEL * D_MODEL / 4);
    cvt_seg(s4, d4, (long)UPN * D_MODEL / 4);
    cvt_seg(s5, d5, (long)D_MODEL * DFF / 4);
}

// ---------------- RMSNorm ----------------
__global__ __launch_bounds__(256) void rmsnorm_kernel(const float* __restrict__ x,
                                                      const float* __restrict__ g,
                                                      bf16_t* __restrict__ out) {
    int row = blockIdx.x;
    const float* xr = x + (size_t)row * D_MODEL;
    int c0 = threadIdx.x * 8;
    float4 a = *(const float4*)&xr[c0];
    float4 b = *(const float4*)&xr[c0 + 4];
    float ss = a.x*a.x + a.y*a.y + a.z*a.z + a.w*a.w
             + b.x*b.x + b.y*b.y + b.z*b.z + b.w*b.w;
    #pragma unroll
    for (int off = 1; off < 64; off <<= 1) ss += __shfl_xor(ss, off);
    __shared__ float red[4];
    if ((threadIdx.x & 63) == 0) red[threadIdx.x >> 6] = ss;
    __syncthreads();
    float norm = rsqrtf((red[0] + red[1] + red[2] + red[3]) * (1.f / D_MODEL) + 1e-6f);
    float4 ga = *(const float4*)&g[c0];
    float4 gb = *(const float4*)&g[c0 + 4];
    bf16x8 o;
    o[0] = (bf16_t)(a.x * ga.x * norm); o[1] = (bf16_t)(a.y * ga.y * norm);
    o[2] = (bf16_t)(a.z * ga.z * norm); o[3] = (bf16_t)(a.w * ga.w * norm);
    o[4] = (bf16_t)(b.x * gb.x * norm); o[5] = (bf16_t)(b.y * gb.y * norm);
    o[6] = (bf16_t)(b.z * gb.z * norm); o[7] = (bf16_t)(b.w * gb.w * norm);
    *(bf16x8*)&out[(size_t)row * D_MODEL + c0] = o;
}

// ---------------- combine: out = r + p0 + p1 (bf16 partials) ----------------
__global__ __launch_bounds__(256) void combine3_kernel(const float* __restrict__ r,
        const bf16_t* __restrict__ p0, const bf16_t* __restrict__ p1,
        float* __restrict__ out, long n8) {
    long i = (long)blockIdx.x * 256 + threadIdx.x;
    long stride = (long)gridDim.x * 256;
    for (; i < n8; i += stride) {
        size_t e = (size_t)i * 8;
        float4 a0 = *(const float4*)&r[e];
        float4 a1 = *(const float4*)&r[e + 4];
        bf16x8 b0 = *(const bf16x8*)&p0[e];
        bf16x8 b1 = *(const bf16x8*)&p1[e];
        float4 o0, o1;
        o0.x = a0.x + (float)b0[0] + (float)b1[0];
        o0.y = a0.y + (float)b0[1] + (float)b1[1];
        o0.z = a0.z + (float)b0[2] + (float)b1[2];
        o0.w = a0.w + (float)b0[3] + (float)b1[3];
        o1.x = a1.x + (float)b0[4] + (float)b1[4];
        o1.y = a1.y + (float)b0[5] + (float)b1[5];
        o1.z = a1.z + (float)b0[6] + (float)b1[6];
        o1.w = a1.w + (float)b0[7] + (float)b1[7];
        *(float4*)&out[e] = o0;
        *(float4*)&out[e + 4] = o1;
    }
}

// ---------------- fused combine(2 partials) + RMSNorm ----------------
__global__ __launch_bounds__(256) void combine_rms_kernel(const float* __restrict__ r,
        const bf16_t* __restrict__ p0, const bf16_t* __restrict__ p1,
        const float* __restrict__ g, float* __restrict__ x1, bf16_t* __restrict__ h2) {
    int row = blockIdx.x;
    size_t rb = (size_t)row * D_MODEL;
    int c0 = threadIdx.x * 8;
    float4 a0 = *(const float4*)&r[rb + c0];
    float4 a1 = *(const float4*)&r[rb + c0 + 4];
    bf16x8 b0 = *(const bf16x8*)&p0[rb + c0];
    bf16x8 b1 = *(const bf16x8*)&p1[rb + c0];
    float v0 = a0.x + (float)b0[0] + (float)b1[0];
    float v1 = a0.y + (float)b0[1] + (float)b1[1];
    float v2 = a0.z + (float)b0[2] + (float)b1[2];
    float v3 = a0.w + (float)b0[3] + (float)b1[3];
    float v4 = a1.x + (float)b0[4] + (float)b1[4];
    float v5 = a1.y + (float)b0[5] + (float)b1[5];
    float v6 = a1.z + (float)b0[6] + (float)b1[6];
    float v7 = a1.w + (float)b0[7] + (float)b1[7];
    float4 w0; w0.x = v0; w0.y = v1; w0.z = v2; w0.w = v3;
    float4 w1; w1.x = v4; w1.y = v5; w1.z = v6; w1.w = v7;
    *(float4*)&x1[rb + c0] = w0;
    *(float4*)&x1[rb + c0 + 4] = w1;
    float ss = v0*v0 + v1*v1 + v2*v2 + v3*v3 + v4*v4 + v5*v5 + v6*v6 + v7*v7;
    #pragma unroll
    for (int off = 1; off < 64; off <<= 1) ss += __shfl_xor(ss, off);
    __shared__ float red[4];
    if ((threadIdx.x & 63) == 0) red[threadIdx.x >> 6] = ss;
    __syncthreads();
    float norm = rsqrtf((red[0] + red[1] + red[2] + red[3]) * (1.f / D_MODEL) + 1e-6f);
    float4 ga = *(const float4*)&g[c0];
    float4 gb = *(const float4*)&g[c0 + 4];
    bf16x8 o;
    o[0] = (bf16_t)(v0 * ga.x * norm); o[1] = (bf16_t)(v1 * ga.y * norm);
    o[2] = (bf16_t)(v2 * ga.z * norm); o[3] = (bf16_t)(v3 * ga.w * norm);
    o[4] = (bf16_t)(v4 * gb.x * norm); o[5] = (bf16_t)(v5 * gb.y * norm);
    o[6] = (bf16_t)(v6 * gb.z * norm); o[7] = (bf16_t)(v7 * gb.w * norm);
    *(bf16x8*)&h2[rb + c0] = o;
}

// ---------------- 256x256 GEMM, deep-staged 4-phase pipeline (r7 structure, FROZEN) ----
// 512 thr = 8 waves (2M x 4N), wave owns 128x64. LDS 128 KB (1 block/CU): [buf][khalf][256][32].
// Stage slots: P1: A1(t+1)  P2: B1(t+1)  P3: A0(t+2)  P4: B0(t+2)
// Waits: end-P2 vmcnt(8); end-P4 vmcnt(8) — drain loads issued 5-6 phases back.
// Tail: t=NKT-2 W2=vmcnt(4); t=NKT-1 W1=W2=vmcnt(0). Two barriers per K-tile.
// (8-barrier variants regressed twice — r8/r12 338µs vs this 313µs. FROZEN.)
// Granule swizzle: LDS granule g of row r holds source granule g ^ ((r>>1)&3).
// MODE 0: fused QKV (N=6144), q scaled, v scattered to [b,h,d,s].
// MODE 1 KSPLIT=2: bf16 partial per z.   MODE 2: upgate gelu(u)*v.
template<int MODE, int KSPLIT>
__global__ __launch_bounds__(512, 2)
void gemm256(const bf16_t* __restrict__ A, const bf16_t* __restrict__ W,
             void* __restrict__ o0, void* __restrict__ o1, void* __restrict__ o2,
             const float* __restrict__ res, int nbx, int K)
{
    __shared__ __align__(16) bf16_t ldsA[2 * 2 * 8192];
    __shared__ __align__(16) bf16_t ldsB[2 * 2 * 8192];
    const int tid = threadIdx.x;
    const int wave = tid >> 6, lane = tid & 63;
    const int lr = lane & 15, lg = lane >> 4;
    const int wm = wave >> 2, wn = wave & 3;

    const int nwg = gridDim.x, bid = blockIdx.x;
    const int cpx = nwg >> 3;
    const int s = (bid & 7) * cpx + (bid >> 3);
    const int by = s & 15, bx = s >> 4;      // by fast: B panel stays L2-resident per XCD
    const int bm0 = by * 256;
    const int bn0 = (MODE == 2) ? bx * 128 : bx * 256;
    const int z = (KSPLIT > 1) ? blockIdx.z : 0;
    const int Keff = K / KSPLIT, koff = z * Keff;

    const int rl = wave * 16 + (lane >> 2);                  // staging row 0..127
    const int gsw = ((lane & 3) ^ ((rl >> 1) & 3)) * 8;      // inverse-swizzled src granule
    const bf16_t* asrc = A + (size_t)(bm0 + rl) * K + koff + gsw;
    const bf16_t* bsrc;
    size_t bstep2;
    if constexpr (MODE == 2) {
        int grp = rl >> 6, wi = rl & 63;
        int brow = (wi < 32) ? (bn0 + grp * 32 + wi) : (DFF + bn0 + grp * 32 + (wi - 32));
        bsrc = W + (size_t)brow * K + koff + gsw;
        bstep2 = (size_t)64 * K;
    } else {
        bsrc = W + (size_t)(bn0 + rl) * K + koff + gsw;
        bstep2 = (size_t)128 * K;
    }

    auto stA = [&](int t, int kh) {
        char* d = (char*)ldsA + (((t & 1) * 2 + kh) * 16384) + wave * 1024 + lane * 16;
        const bf16_t* sp = asrc + (size_t)t * 64 + kh * 32;
        GLDS16(sp, d);
        GLDS16(sp + (size_t)128 * K, d + 8192);
    };
    auto stB = [&](int t, int kh) {
        char* d = (char*)ldsB + (((t & 1) * 2 + kh) * 16384) + wave * 1024 + lane * 16;
        const bf16_t* sp = bsrc + (size_t)t * 64 + kh * 32;
        GLDS16(sp, d);
        GLDS16(sp + bstep2, d + 8192);
    };

    f32x4 acc[8][4] = {};
    const int xg = (lg ^ ((lr >> 1) & 3)) * 8;
    const int NKT = Keff >> 6;

    // prologue: A0(0) B0(0) A1(0) B1(0) A0(1) B0(1) in flight (12 loads); drain first 4
    stA(0, 0); stB(0, 0); stA(0, 1); stB(0, 1); stA(1, 0); stB(1, 0);
    asm volatile("s_waitcnt vmcnt(8)" ::: "memory");
    __builtin_amdgcn_s_barrier();

#define TILE_BODY(T, S1, S2, W1, W2)                                                    \
    {                                                                                   \
        const int t_ = (T);                                                             \
        const bf16_t* Ab = ldsA + ((t_ & 1) * 2) * 8192;                                \
        const bf16_t* Bb = ldsB + ((t_ & 1) * 2) * 8192;                                \
        bf16x8 a0[4], a1[4], b0[4], b1[4];                                              \
        /* P1: kh0 m0-3 */                                                              \
        _Pragma("unroll")                                                               \
        for (int i = 0; i < 4; ++i)                                                     \
            a0[i] = *(const bf16x8*)&Ab[(wm * 128 + i * 16 + lr) * 32 + xg];            \
        _Pragma("unroll")                                                               \
        for (int n = 0; n < 4; ++n)                                                     \
            b0[n] = *(const bf16x8*)&Bb[(wn * 64 + n * 16 + lr) * 32 + xg];             \
        if (S1) stA(t_ + 1, 1);                                                         \
        __builtin_amdgcn_s_setprio(1);                                                  \
        _Pragma("unroll")                                                               \
        for (int i = 0; i < 4; ++i)                                                     \
            _Pragma("unroll")                                                           \
            for (int n = 0; n < 4; ++n)                                                 \
                acc[i][n] = MFMA16(a0[i], b0[n], acc[i][n]);                            \
        __builtin_amdgcn_s_setprio(0);                                                  \
        /* P2: kh0 m4-7 */                                                              \
        _Pragma("unroll")                                                               \
        for (int i = 0; i < 4; ++i)                                                     \
            a1[i] = *(const bf16x8*)&Ab[(wm * 128 + (i + 4) * 16 + lr) * 32 + xg];      \
        if (S1) stB(t_ + 1, 1);                                                         \
        __builtin_amdgcn_s_setprio(1);                                                  \
        _Pragma("unroll")                                                               \
        for (int i = 0; i < 4; ++i)                                                     \
            _Pragma("unroll")                                                           \
            for (int n = 0; n < 4; ++n)                                                 \
                acc[i + 4][n] = MFMA16(a1[i], b0[n], acc[i + 4][n]);                    \
        __builtin_amdgcn_s_setprio(0);                                                  \
        asm volatile("s_waitcnt vmcnt(" W1 ")" ::: "memory");                           \
        __builtin_amdgcn_s_barrier();                                                   \
        /* P3: kh1 m0-3 */                                                              \
        _Pragma("unroll")                                                               \
        for (int i = 0; i < 4; ++i)                                                     \
            a0[i] = *(const bf16x8*)&Ab[8192 + (wm * 128 + i * 16 + lr) * 32 + xg];     \
        _Pragma("unroll")                                                               \
        for (int n = 0; n < 4; ++n)                                                     \
            b1[n] = *(const bf16x8*)&Bb[8192 + (wn * 64 + n * 16 + lr) * 32 + xg];      \
        if (S2) stA(t_ + 2, 0);                                                         \
        __builtin_amdgcn_s_setprio(1);                                                  \
        _Pragma("unroll")                                                               \
        for (int i = 0; i < 4; ++i)                                                     \
            _Pragma("unroll")                                                           \
            for (int n = 0; n < 4; ++n)                                                 \
                acc[i][n] = MFMA16(a0[i], b1[n], acc[i][n]);                            \
        __builtin_amdgcn_s_setprio(0);                                                  \
        /* P4: kh1 m4-7 */                                                              \
        _Pragma("unroll")                                                               \
        for (int i = 0; i < 4; ++i)                                                     \
            a1[i] = *(const bf16x8*)&Ab[8192 + (wm * 128 + (i + 4) * 16 + lr) * 32 + xg]; \
        if (S2) stB(t_ + 2, 0);                                                         \
        __builtin_amdgcn_s_setprio(1);                                                  \
        _Pragma("unroll")                                                               \
        for (int i = 0; i < 4; ++i)                                                     \
            _Pragma("unroll")                                                           \
            for (int n = 0; n < 4; ++n)                                                 \
                acc[i + 4][n] = MFMA16(a1[i], b1[n], acc[i + 4][n]);                    \
        __builtin_amdgcn_s_setprio(0);                                                  \
        asm volatile("s_waitcnt vmcnt(" W2 ")" ::: "memory");                           \
        __builtin_amdgcn_s_barrier();                                                   \
    }

    for (int t = 0; t < NKT - 2; ++t) TILE_BODY(t, true, true, "8", "8");
    TILE_BODY(NKT - 2, true, false, "8", "4");
    TILE_BODY(NKT - 1, false, false, "0", "0");
#undef TILE_BODY

    // ---------------- epilogue ----------------
    if constexpr (MODE == 0) {
        const float qs = 0.08838834764831845f;
        const int th = bn0 >> 11;
        #pragma unroll
        for (int m = 0; m < 8; ++m) {
            int grow = bm0 + wm * 128 + m * 16 + lg * 4;
            #pragma unroll
            for (int n = 0; n < 4; ++n) {
                int gcol = bn0 + wn * 64 + n * 16 + lr;
                int c = gcol & 2047;
                if (th == 0) {
                    #pragma unroll
                    for (int r = 0; r < 4; ++r)
                        ((bf16_t*)o0)[(size_t)(grow + r) * D_MODEL + c] = (bf16_t)(acc[m][n][r] * qs);
                } else if (th == 1) {
                    #pragma unroll
                    for (int r = 0; r < 4; ++r)
                        ((bf16_t*)o1)[(size_t)(grow + r) * D_MODEL + c] = (bf16_t)acc[m][n][r];
                } else {
                    int hh = c >> 7, d = c & 127;
                    int bb = grow >> 11, t0 = grow & 2047;
                    bf16x4 st;
                    #pragma unroll
                    for (int r = 0; r < 4; ++r) st[r] = (bf16_t)acc[m][n][r];
                    *(bf16x4*)&((bf16_t*)o2)[((size_t)(bb * N_HEADS + hh) * HEAD_D + d) * SEQ + t0] = st;
                }
            }
        }
    } else if constexpr (MODE == 1) {
        bf16_t* po = (bf16_t*)o0 + (size_t)z * PSTRIDE;
        #pragma unroll
        for (int m = 0; m < 8; ++m) {
            int grow = bm0 + wm * 128 + m * 16 + lg * 4;
            #pragma unroll
            for (int n = 0; n < 4; ++n) {
                int gcol = bn0 + wn * 64 + n * 16 + lr;
                #pragma unroll
                for (int r = 0; r < 4; ++r) {
                    size_t idx = (size_t)(grow + r) * D_MODEL + gcol;
                    po[idx] = (bf16_t)acc[m][n][r];
                }
            }
        }
    } else {
        #pragma unroll
        for (int m = 0; m < 8; ++m) {
            int grow = bm0 + wm * 128 + m * 16 + lg * 4;
            #pragma unroll
            for (int n = 0; n < 2; ++n) {
                int gcol = bn0 + wn * 32 + n * 16 + lr;
                #pragma unroll
                for (int r = 0; r < 4; ++r) {
                    float u = acc[m][n][r], vg = acc[m][n + 2][r];
                    float ge = 0.5f * u * (1.f + erff(u * 0.70710678118654752f));
                    ((bf16_t*)o0)[(size_t)(grow + r) * DFF + gcol] = (bf16_t)(ge * vg);
                }
            }
        }
    }
}

// ---------------- Flash attention (causal), Q-block 128, KV-block 64 ----------------
// Balanced qb mapping: qb = bz ? bx : 15-bx — each CU's co-resident pair (block i,
// block i+256) sums to a constant 16+2 tiles of work (was 48-vs-20 imbalance).
// T14 named-register prefetch; T13 defer-max. LDS 78.8 KB -> 2 blocks/CU.
#define SM_PV(svv, mr, lrr, oo)                                                         \
    {                                                                                   \
        float resc_[4]; bool dall_ = true;                                              \
        _Pragma("unroll")                                                               \
        for (int r = 0; r < 4; ++r) {                                                   \
            float mx = fmaxf(fmaxf(svv[0][r], svv[1][r]), fmaxf(svv[2][r], svv[3][r]));  \
            _Pragma("unroll")                                                           \
            for (int off = 1; off < 16; off <<= 1) mx = fmaxf(mx, __shfl_xor(mx, off)); \
            bool defer = __all(mx - mr[r] <= 8.f);                                      \
            float mnew = defer ? mr[r] : fmaxf(mr[r], mx);                              \
            resc_[r] = defer ? 1.f : __expf(mr[r] - mnew);                              \
            dall_ &= defer;                                                             \
            float sum = 0.f;                                                            \
            _Pragma("unroll")                                                           \
            for (int nb = 0; nb < 4; ++nb) {                                            \
                float p = __expf(svv[nb][r] - mnew);                                    \
                svv[nb][r] = p; sum += p;                                               \
            }                                                                           \
            _Pragma("unroll")                                                           \
            for (int off = 1; off < 16; off <<= 1) sum += __shfl_xor(sum, off);         \
            lrr[r] = lrr[r] * resc_[r] + sum; mr[r] = mnew;                             \
        }                                                                               \
        if (!dall_) {                                                                   \
            _Pragma("unroll")                                                           \
            for (int ob = 0; ob < 8; ++ob)                                              \
                _Pragma("unroll")                                                       \
                for (int r = 0; r < 4; ++r) oo[ob][r] *= resc_[r];                      \
        }                                                                               \
        _Pragma("unroll")                                                               \
        for (int nb = 0; nb < 4; ++nb)                                                  \
            _Pragma("unroll")                                                           \
            for (int r = 0; r < 4; ++r)                                                 \
                Ps[wave][(lg * 4 + r) * 72 + nb * 16 + lr] = (bf16_t)svv[nb][r];        \
        _Pragma("unroll")                                                               \
        for (int kk = 0; kk < 2; ++kk) {                                                \
            bf16x8 ap = *(const bf16x8*)&Ps[wave][lr * 72 + kk * 32 + lg * 8];          \
            _Pragma("unroll")                                                           \
            for (int ob = 0; ob < 8; ++ob) {                                            \
                bf16x8 bv = *(const bf16x8*)&Vts[(ob * 16 + lr) * 68 + kk * 32 + lg * 8]; \
                oo[ob] = MFMA16(ap, bv, oo[ob]);                                        \
            }                                                                           \
        }                                                                               \
    }

__global__ __launch_bounds__(256)
void attn_kernel(const bf16_t* __restrict__ Q, const bf16_t* __restrict__ K,
                 const bf16_t* __restrict__ Vt, bf16_t* __restrict__ Z)
{
    // balanced pairing: b=0 gets descending qb, b=1 ascending -> co-resident sums const
    const int qb = blockIdx.z ? blockIdx.x : (gridDim.x - 1 - blockIdx.x);
    const int h = blockIdx.y, b = blockIdx.z;
    const int q0 = qb * 128;
    const int ktmax = 2 * qb + 1;                // inclusive last K/V tile
    const int tid = threadIdx.x, wave = tid >> 6, lane = tid & 63;
    const int lr = lane & 15, lg = lane >> 4;

    __shared__ __align__(16) bf16_t Qs[128 * 136];
    __shared__ __align__(16) bf16_t Ks[64 * 136];
    __shared__ __align__(16) bf16_t Vts[128 * 68];
    __shared__ __align__(16) bf16_t Ps[4][16 * 72];

    const size_t base = ((size_t)b * SEQ) * D_MODEL + (size_t)h * HEAD_D;
    const size_t vbase = (size_t)(b * N_HEADS + h) * HEAD_D * SEQ;

    const int kr = tid >> 4, kc = (tid & 15) * 8;
    const int vdr = tid >> 3, vc = (tid & 7) * 8;

    #pragma unroll
    for (int i = 0; i < 8; ++i)
        *(uint4*)&Qs[(kr + i * 16) * 136 + kc] =
            *(const uint4*)&Q[base + (size_t)(q0 + kr + i * 16) * D_MODEL + kc];

    uint4 k0g, k1g, k2g, k3g, v0g, v1g, v2g, v3g;   // named => guaranteed VGPRs
    const bf16_t* Kb = K + base + (size_t)kr * D_MODEL + kc;
    const bf16_t* Vb = Vt + vbase + (size_t)vdr * SEQ + vc;
    auto loadKV = [&](int kt) {
        const bf16_t* kp = Kb + (size_t)kt * 64 * D_MODEL;
        k0g = *(const uint4*)kp;
        k1g = *(const uint4*)(kp + (size_t)16 * D_MODEL);
        k2g = *(const uint4*)(kp + (size_t)32 * D_MODEL);
        k3g = *(const uint4*)(kp + (size_t)48 * D_MODEL);
        const bf16_t* vp = Vb + kt * 64;
        v0g = *(const uint4*)vp;
        v1g = *(const uint4*)(vp + (size_t)32 * SEQ);
        v2g = *(const uint4*)(vp + (size_t)64 * SEQ);
        v3g = *(const uint4*)(vp + (size_t)96 * SEQ);
    };
    loadKV(0);

    f32x4 oL[8] = {}, oH[8] = {};
    float mL[4], lL[4], mH[4], lH[4];
    #pragma unroll
    for (int r = 0; r < 4; ++r) { mL[r] = -1e30f; lL[r] = 0.f; mH[r] = -1e30f; lH[r] = 0.f; }

    for (int kt = 0; kt <= ktmax; ++kt) {
        __syncthreads();   // previous tile's LDS reads complete
        *(uint4*)&Ks[kr * 136 + kc] = k0g;
        *(uint4*)&Ks[(kr + 16) * 136 + kc] = k1g;
        *(uint4*)&Ks[(kr + 32) * 136 + kc] = k2g;
        *(uint4*)&Ks[(kr + 48) * 136 + kc] = k3g;
        *(uint4*)&Vts[vdr * 68 + vc] = v0g;
        *(uint4*)&Vts[(vdr + 32) * 68 + vc] = v1g;
        *(uint4*)&Vts[(vdr + 64) * 68 + vc] = v2g;
        *(uint4*)&Vts[(vdr + 96) * 68 + vc] = v3g;
        __syncthreads();
        if (kt < ktmax) loadKV(kt + 1);   // in flight across this tile's compute

        // ---- tile L (rows q0 .. q0+63): active while kt < ktmax ----
        if (kt < ktmax) {
            f32x4 sv[4] = {};
            #pragma unroll
            for (int kk = 0; kk < 4; ++kk) {
                bf16x8 aq = *(const bf16x8*)&Qs[(wave * 16 + lr) * 136 + kk * 32 + lg * 8];
                #pragma unroll
                for (int nb = 0; nb < 4; ++nb) {
                    bf16x8 bk = *(const bf16x8*)&Ks[(nb * 16 + lr) * 136 + kk * 32 + lg * 8];
                    sv[nb] = MFMA16(aq, bk, sv[nb]);
                }
            }
            if (kt == ktmax - 1) {   // diagonal of L
                #pragma unroll
                for (int nb = 0; nb < 4; ++nb)
                    #pragma unroll
                    for (int r = 0; r < 4; ++r) {
                        int qrel = 16 * wave + lg * 4 + r;
                        int krel = nb * 16 + lr;
                        if (krel > qrel) sv[nb][r] = -1e30f;
                    }
            }
            SM_PV(sv, mL, lL, oL)
        }
        // ---- tile H (rows q0+64 .. q0+127): always active ----
        {
            f32x4 sv[4] = {};
            #pragma unroll
            for (int kk = 0; kk < 4; ++kk) {
                bf16x8 aq = *(const bf16x8*)&Qs[(64 + wave * 16 + lr) * 136 + kk * 32 + lg * 8];
                #pragma unroll
                for (int nb = 0; nb < 4; ++nb) {
                    bf16x8 bk = *(const bf16x8*)&Ks[(nb * 16 + lr) * 136 + kk * 32 + lg * 8];
                    sv[nb] = MFMA16(aq, bk, sv[nb]);
                }
            }
            if (kt == ktmax) {   // diagonal of H
                #pragma unroll
                for (int nb = 0; nb < 4; ++nb)
                    #pragma unroll
                    for (int r = 0; r < 4; ++r) {
                        int qrel = 16 * wave + lg * 4 + r;
                        int krel = nb * 16 + lr;
                        if (krel > qrel) sv[nb][r] = -1e30f;
                    }
            }
            SM_PV(sv, mH, lH, oH)
        }
    }
    #pragma unroll
    for (int r = 0; r < 4; ++r) { lL[r] = 1.f / lL[r]; lH[r] = 1.f / lH[r]; }
    #pragma unroll
    for (int ob = 0; ob < 8; ++ob)
        #pragma unroll
        for (int r = 0; r < 4; ++r) {
            int t = q0 + 16 * wave + lg * 4 + r;
            Z[base + (size_t)t * D_MODEL + ob * 16 + lr] = (bf16_t)(oL[ob][r] * lL[r]);
            Z[base + (size_t)(t + 64) * D_MODEL + ob * 16 + lr] = (bf16_t)(oH[ob][r] * lH[r]);
        }
}
#undef SM_PV

// ---------------- host launch ----------------
extern "C" void kernel_launch(void* const* d_in, const int* in_sizes, int n_in,
                              void* d_out, int out_size, void* d_ws, size_t ws_size,
                              hipStream_t stream)
{
    const float* x   = (const float*)d_in[0];
    const float* g1  = (const float*)d_in[1];
    const float* wq  = (const float*)d_in[2];
    const float* wk  = (const float*)d_in[3];
    const float* wv  = (const float*)d_in[4];
    const float* wo  = (const float*)d_in[5];
    const float* g2  = (const float*)d_in[6];
    const float* wup = (const float*)d_in[7];
    const float* wdn = (const float*)d_in[8];
    float* out = (float*)d_out;

    char* wsp = (char*)d_ws;
    size_t off = 0;
    auto alloc = [&](size_t bytes) { void* p = wsp + off; off += (bytes + 255) & ~255ull; return p; };
    // wq_b/wk_b/wv_b contiguous (fused QKV = [6144][2048])
    bf16_t* wq_b  = (bf16_t*)alloc((size_t)D_MODEL * D_MODEL * 2);
    bf16_t* wk_b  = (bf16_t*)alloc((size_t)D_MODEL * D_MODEL * 2);
    bf16_t* wv_b  = (bf16_t*)alloc((size_t)D_MODEL * D_MODEL * 2);
    bf16_t* wo_b  = (bf16_t*)alloc((size_t)D_MODEL * D_MODEL * 2);
    bf16_t* wup_b = (bf16_t*)alloc((size_t)UPN * D_MODEL * 2);
    bf16_t* wdn_b = (bf16_t*)alloc((size_t)D_MODEL * DFF * 2);
    bf16_t* h_b   = (bf16_t*)alloc((size_t)NTOK * D_MODEL * 2);
    bf16_t* q_b   = (bf16_t*)alloc((size_t)NTOK * D_MODEL * 2);
    bf16_t* k_b   = (bf16_t*)alloc((size_t)NTOK * D_MODEL * 2);
    bf16_t* vt_b  = (bf16_t*)alloc((size_t)NTOK * D_MODEL * 2);   // [b,h,d,s]
    bf16_t* z_b   = (bf16_t*)alloc((size_t)NTOK * D_MODEL * 2);
    float*  x1    = (float*) alloc((size_t)NTOK * D_MODEL * 4);
    bf16_t* h2_b  = (bf16_t*)alloc((size_t)NTOK * D_MODEL * 2);
    bf16_t* act_b = (bf16_t*)alloc((size_t)NTOK * DFF * 2);
    // split-K bf16 partials (2 x 16.8 MB) reuse h_b+q_b (dead at those points)
    bf16_t* pbuf = h_b;

    // all weight converts in one launch
    cvt6_kernel<<<2048, 256, 0, stream>>>(wq, wq_b, wk, wk_b, wv, wv_b,
                                          wo, wo_b, wup, wup_b, wdn, wdn_b);

    // h = rmsnorm(x, g1)
    rmsnorm_kernel<<<NTOK, 256, 0, stream>>>(x, g1, h_b);

    // fused QKV: N=6144
    gemm256<0, 1><<<24 * 16, 512, 0, stream>>>(h_b, wq_b, q_b, k_b, vt_b, nullptr, 24, D_MODEL);

    // attention (Q-block 128, balanced qb pairing)
    attn_kernel<<<dim3(SEQ / 128, N_HEADS, 2), 256, 0, stream>>>(q_b, k_b, vt_b, z_b);

    // x1 = x + z @ wo^T (split-K=2, bf16 partials) fused combine+rmsnorm -> h2
    gemm256<1, 2><<<dim3(8 * 16, 1, 2), 512, 0, stream>>>(z_b, wo_b, pbuf, nullptr, nullptr, nullptr, 8, D_MODEL);
    combine_rms_kernel<<<NTOK, 256, 0, stream>>>(x, pbuf, pbuf + PSTRIDE, g2, x1, h2_b);

    // act = gelu(h2 @ Wu^T) * (h2 @ Wv^T)
    gemm256<2, 1><<<64 * 16, 512, 0, stream>>>(h2_b, wup_b, act_b, nullptr, nullptr, nullptr, 64, D_MODEL);

    // out = x1 + act @ w_down^T (split-K=2 + combine)
    gemm256<1, 2><<<dim3(8 * 16, 1, 2), 512, 0, stream>>>(act_b, wdn_b, pbuf, nullptr, nullptr, nullptr, 8, DFF);
    combine3_kernel<<<2048, 256, 0, stream>>>(x1, pbuf, pbuf + PSTRIDE, out,
                                              (long)NTOK * D_MODEL / 8);
}